// Round 3
// baseline (435.352 us; speedup 1.0000x reference)
//
#include <hip/hip_runtime.h>
#include <hip/hip_bf16.h>
#include <stdint.h>

// Problem dims
#define Bn  8
#define Ln  4096
#define DHn 1024
#define Tn  1024
#define DGn 768
#define Pn  256

typedef float  f32x4  __attribute__((ext_vector_type(4)));
typedef __bf16 bf16x8 __attribute__((ext_vector_type(8)));

__device__ __forceinline__ void gload16(const void* g, void* l) {
  __builtin_amdgcn_global_load_lds(
      (const __attribute__((address_space(1))) void*)g,
      (__attribute__((address_space(3))) void*)l, 16, 0, 0);
}

__device__ __forceinline__ unsigned short f2bf(float x) {
  union { float f; uint32_t u; } v; v.f = x;
  uint32_t u = v.u;
  return (unsigned short)((u + 0x7FFFu + ((u >> 16) & 1u)) >> 16);
}

__device__ __forceinline__ float bf2f(unsigned short b) {
  union { uint32_t u; float f; } v; v.u = ((uint32_t)b) << 16;
  return v.f;
}

// ---------------- fused fp32 -> bf16 convert for G, Wq, Wk (one launch) ----------------
__global__ void cvt3_kernel(const float4* __restrict__ a, ushort4* __restrict__ ao, int na4,
                            const float4* __restrict__ b, ushort4* __restrict__ bo, int nb4,
                            const float4* __restrict__ c, ushort4* __restrict__ co, int nc4) {
  int i = blockIdx.x * 256 + threadIdx.x;
  const float4* s; ushort4* d; int j;
  if (i < na4)                  { s = a; d = ao; j = i; }
  else if (i < na4 + nb4)       { s = b; d = bo; j = i - na4; }
  else if (i < na4 + nb4 + nc4) { s = c; d = co; j = i - na4 - nb4; }
  else return;
  float4 v = s[j];
  ushort4 o;
  o.x = f2bf(v.x); o.y = f2bf(v.y); o.z = f2bf(v.z); o.w = f2bf(v.w);
  d[j] = o;
}

// ------- H [B,L,DH] fp32 -> Hb [B,L,DH] bf16 AND HT [B,DH,L] bf16, one read -------
__global__ void prep_H(const float* __restrict__ Hg,
                       unsigned short* __restrict__ Hb,
                       unsigned short* __restrict__ HT) {
  __shared__ unsigned short tile[64 * 65];
  const int b  = blockIdx.z;
  const int l0 = blockIdx.x * 64;
  const int d0 = blockIdx.y * 64;
  const float4* src  = (const float4*)(Hg + (size_t)b * Ln * DHn);
  ushort4*      dstH = (ushort4*)(Hb + (size_t)b * Ln * DHn);
  for (int e = threadIdx.x; e < 1024; e += 256) {
    int l  = e >> 4;
    int d4 = e & 15;
    size_t idx4 = ((size_t)(l0 + l) * DHn + d0) / 4 + d4;
    float4 v = src[idx4];
    ushort4 o;
    o.x = f2bf(v.x); o.y = f2bf(v.y); o.z = f2bf(v.z); o.w = f2bf(v.w);
    dstH[idx4] = o;  // straight bf16 copy
    int d = d4 * 4;
    tile[(d + 0) * 65 + l] = o.x;
    tile[(d + 1) * 65 + l] = o.y;
    tile[(d + 2) * 65 + l] = o.z;
    tile[(d + 3) * 65 + l] = o.w;
  }
  __syncthreads();
  ushort4* dst = (ushort4*)(HT + (size_t)b * DHn * Ln);
  for (int e = threadIdx.x; e < 1024; e += 256) {
    int d  = e >> 4;
    int l4 = (e & 15) * 4;
    ushort4 o;
    o.x = tile[d * 65 + l4 + 0];
    o.y = tile[d * 65 + l4 + 1];
    o.z = tile[d * 65 + l4 + 2];
    o.w = tile[d * 65 + l4 + 3];
    dst[((size_t)(d0 + d) * Ln + l0) / 4 + (e & 15)] = o;
  }
}

// ---------- bt-GEMM: C[m,n] = sum_k A[m,k]*B[n,k], 128 x (NT*32) tile, BK k-step ----------
// Flat grid, batch-on-XCD swizzle: b = x&7, then n-tile innermost (consecutive
// blocks on one XCD share the A-tile -> L2-resident re-reads).
// 2-barrier single-buffer structure: R6 post-mortem — explicit dbuf/counted-vmcnt
// variants are null-to-negative here (m99/m139/m232 + measured R5 regression
// 93->167us); latency hiding comes from multi-block TLP. The m112 data point
// (256^2 tile @ 1 blk/CU = 792 TF) shows the 2-barrier template tolerates low
// residency when arithmetic intensity is high — hence Z at 128x128 (2 blk/CU).
// Bank-conflict-free staging swizzles (R3 verified conflicts 8.4M -> 0):
//   BK=32: row stride 64B; lane stages kgroup (lane&3)^((lane>>3)&3);
//          fragment slot = quad^((lrow>>1)&3).
//   BK=64: row stride 128B (banks wrap per row); lane stages kgroup
//          (lane&7)^((lane>>3)&7); fragment slot = (h*4+quad)^(lrow&7).
// EPI 0: C bf16 = acc
// EPI 1: C bf16 = exp(acc*scale), row-sums atomically added into S
// EPI 2: C fp32 = acc / (S[row] + 1e-8)
template <int EPI, int NT, int BK>
__global__ __launch_bounds__(256) void gemm_bt(
    const unsigned short* __restrict__ A, const unsigned short* __restrict__ B,
    void* __restrict__ Cout, float* __restrict__ S,
    int kLen, int lda, int ldb, int ldc,
    long sA, long sB, long sC, int sS, float scale, int nTiles) {
  constexpr int Nn  = NT * 32;             // block n-extent
  constexpr int RPC = 1024 / (BK * 2);     // rows per 1KB staging chunk
  constexpr int APW = (128 * BK * 2 / 1024) / 4;  // A chunks per wave
  constexpr int BPW = (Nn  * BK * 2 / 1024) / 4;  // B chunks per wave
  __shared__ unsigned short As[128 * BK];
  __shared__ unsigned short Bs[Nn * BK];
  int x = blockIdx.x;
  const int b = x & (Bn - 1);
  int r = x >> 3;
  const int ni = r % nTiles;
  const int mi = r / nTiles;
  const unsigned short* Ab = A + (long)b * sA;
  const unsigned short* Bb = B + (long)b * sB;
  const int m0 = mi * 128;
  const int n0 = ni * Nn;
  const int tid  = threadIdx.x;
  const int lane = tid & 63;
  const int wave = tid >> 6;
  const int wm = (wave >> 1) << 6;        // wave m-offset (2 waves over 128 rows)
  const int wn = (wave & 1) * (NT * 16);  // wave n-offset (2 waves over Nn cols)
  const int lrow = lane & 15;
  const int quad = lane >> 4;
  // staging: row within chunk + swizzled k-offset (see header comment)
  const int srow  = (BK == 32) ? (lane >> 2) : (lane >> 3);
  const int skcol = (BK == 32)
      ? (((lane & 3) ^ ((lane >> 3) & 3)) << 3)
      : (((lane & 7) ^ ((lane >> 3) & 7)) << 3);

  f32x4 acc[4][NT];
#pragma unroll
  for (int mt = 0; mt < 4; ++mt)
#pragma unroll
    for (int nt = 0; nt < NT; ++nt) acc[mt][nt] = f32x4{0.f, 0.f, 0.f, 0.f};

  for (int k0 = 0; k0 < kLen; k0 += BK) {
    __syncthreads();
#pragma unroll
    for (int j = 0; j < APW; ++j) {
      int c = wave * APW + j;
      gload16(Ab + (size_t)(m0 + c * RPC + srow) * lda + (k0 + skcol), &As[c * 512]);
    }
#pragma unroll
    for (int j = 0; j < BPW; ++j) {
      int c = wave * BPW + j;
      gload16(Bb + (size_t)(n0 + c * RPC + srow) * ldb + (k0 + skcol), &Bs[c * 512]);
    }
    __syncthreads();
#pragma unroll
    for (int h = 0; h < BK / 32; ++h) {
      const int fsl = (BK == 32)
          ? ((quad ^ ((lrow >> 1) & 3)) << 3)
          : ((((h << 2) + quad) ^ (lrow & 7)) << 3);
      bf16x8 af[4], bfr[NT];
#pragma unroll
      for (int mt = 0; mt < 4; ++mt)
        af[mt] = *(const bf16x8*)&As[(wm + mt * 16 + lrow) * BK + fsl];
#pragma unroll
      for (int nt = 0; nt < NT; ++nt)
        bfr[nt] = *(const bf16x8*)&Bs[(wn + nt * 16 + lrow) * BK + fsl];
#pragma unroll
      for (int mt = 0; mt < 4; ++mt)
#pragma unroll
        for (int nt = 0; nt < NT; ++nt)
          acc[mt][nt] = __builtin_amdgcn_mfma_f32_16x16x32_bf16(
              af[mt], bfr[nt], acc[mt][nt], 0, 0, 0);
    }
  }

  // C/D layout (verified m89/m91): col = lane&15, row = quad*4 + reg
  if (EPI == 0) {
    unsigned short* C = (unsigned short*)Cout + (long)b * sC;
#pragma unroll
    for (int mt = 0; mt < 4; ++mt)
#pragma unroll
      for (int r2 = 0; r2 < 4; ++r2) {
        int row = m0 + wm + mt * 16 + quad * 4 + r2;
        unsigned short* Cr = C + (size_t)row * ldc + n0 + wn + lrow;
#pragma unroll
        for (int nt = 0; nt < NT; ++nt) Cr[nt * 16] = f2bf(acc[mt][nt][r2]);
      }
  } else if (EPI == 1) {
    unsigned short* C = (unsigned short*)Cout + (long)b * sC;
    float* Sb = S + (long)b * sS;
#pragma unroll
    for (int mt = 0; mt < 4; ++mt)
#pragma unroll
      for (int r2 = 0; r2 < 4; ++r2) {
        int row = m0 + wm + mt * 16 + quad * 4 + r2;
        unsigned short* Cr = C + (size_t)row * ldc + n0 + wn + lrow;
        float psum = 0.f;
#pragma unroll
        for (int nt = 0; nt < NT; ++nt) {
          float e = __expf(acc[mt][nt][r2] * scale);
          unsigned short bv = f2bf(e);
          Cr[nt * 16] = bv;
          psum += bf2f(bv);  // sum the value we actually stored
        }
        psum += __shfl_xor(psum, 1);
        psum += __shfl_xor(psum, 2);
        psum += __shfl_xor(psum, 4);
        psum += __shfl_xor(psum, 8);
        if (lrow == 0) atomicAdd(&Sb[row], psum);
      }
  } else {
    float* C = (float*)Cout + (long)b * sC;
    const float* Sb = S + (long)b * sS;
#pragma unroll
    for (int mt = 0; mt < 4; ++mt)
#pragma unroll
      for (int r2 = 0; r2 < 4; ++r2) {
        int row = m0 + wm + mt * 16 + quad * 4 + r2;
        float inv = 1.f / (Sb[row] + 1e-8f);
        float* Cr = C + (size_t)row * ldc + n0 + wn + lrow;
#pragma unroll
        for (int nt = 0; nt < NT; ++nt) Cr[nt * 16] = acc[mt][nt][r2] * inv;
      }
  }
}

extern "C" void kernel_launch(void* const* d_in, const int* in_sizes, int n_in,
                              void* d_out, int out_size, void* d_ws, size_t ws_size,
                              hipStream_t stream) {
  const float* H  = (const float*)d_in[0];
  const float* G  = (const float*)d_in[1];
  const float* Wq = (const float*)d_in[2];
  const float* Wk = (const float*)d_in[3];
  float* out = (float*)d_out;

  char* ws = (char*)d_ws;
  size_t off = 0;
  auto alloc = [&](size_t bytes) {
    void* p = ws + off;
    off = (off + bytes + 255) & ~(size_t)255;
    return p;
  };
  unsigned short* Hb  = (unsigned short*)alloc((size_t)Bn * Ln * DHn * 2); // 64MB
  unsigned short* HbT = (unsigned short*)alloc((size_t)Bn * DHn * Ln * 2); // 64MB
  unsigned short* Gb  = (unsigned short*)alloc((size_t)Bn * Tn * DGn * 2); // 12MB
  unsigned short* Wqb = (unsigned short*)alloc((size_t)Pn * DGn * 2);
  unsigned short* Wkb = (unsigned short*)alloc((size_t)Pn * DHn * 2);
  unsigned short* Kb  = (unsigned short*)alloc((size_t)Bn * Ln * Pn * 2);  // 16MB
  unsigned short* Qb  = (unsigned short*)alloc((size_t)Bn * Tn * Pn * 2);  // 4MB
  float* Sv           = (float*)alloc((size_t)Bn * Tn * 4);                // 32KB
  // P [B,T,L] bf16 (64MB) aliases Hb: Hb is dead after K-proj, and same-stream
  // kernels serialize, so QK's writes can't race K-proj's reads.
  unsigned short* Pm = Hb;

  // 1) fused small converts (G, Wq, Wk) in one launch
  {
    int na4 = Bn * Tn * DGn / 4;   // 1572864
    int nb4 = Pn * DGn / 4;        // 49152
    int nc4 = Pn * DHn / 4;        // 65536
    int tot = na4 + nb4 + nc4;     // 1687552 = 6592 * 256
    cvt3_kernel<<<(tot + 255) / 256, 256, 0, stream>>>(
        (const float4*)G, (ushort4*)Gb, na4,
        (const float4*)Wq, (ushort4*)Wqb, nb4,
        (const float4*)Wk, (ushort4*)Wkb, nc4);
  }
  // 2) fused H convert + transpose (reads H fp32 exactly once)
  prep_H<<<dim3(Ln / 64, DHn / 64, Bn), 256, 0, stream>>>(H, Hb, HbT);
  // 3) zero softmax sums
  hipMemsetAsync(Sv, 0, (size_t)Bn * Tn * 4, stream);

  // 4) K = H Wk^T : [L,P] per batch, 128x64 tiles, BK=64 (32 x 4 x 8 = 1024 blocks)
  gemm_bt<0, 2, 64><<<Bn * 32 * 4, 256, 0, stream>>>(
      Hb, Wkb, Kb, nullptr, DHn, DHn, DHn, Pn,
      (long)Ln * DHn, 0L, (long)Ln * Pn, 0, 1.f, 4);
  // 5) Q = G Wq^T : [T,P] per batch, 128x32 tiles, BK=64 (8 x 8 x 8 = 512 blocks)
  gemm_bt<0, 1, 64><<<Bn * 8 * 8, 256, 0, stream>>>(
      Gb, Wqb, Qb, nullptr, DGn, DGn, DGn, Pn,
      (long)Tn * DGn, 0L, (long)Tn * Pn, 0, 1.f, 8);
  // 6) P = exp(scale * Q K^T) : [T,L], 128x128 tiles, BK=64 (4 K-steps instead
  //    of 8; VGPR-capped at ~3 blk/CU either way, so halved barrier count is free)
  gemm_bt<1, 4, 64><<<Bn * 8 * 32, 256, 0, stream>>>(
      Qb, Kb, Pm, Sv, Pn, Pn, Pn, Ln,
      (long)Tn * Pn, (long)Ln * Pn, (long)Tn * Ln, Tn, 0.0625f, 32);
  // 7) Z = (P H) / (s + eps) : [T,DH], 128x128 tiles, BK=64 (8 x 8 x 8 = 512
  //    blocks, 2/CU) — plain m97 structure (912 TF proven), 32KB LDS, AI=64 F/B
  gemm_bt<2, 4, 64><<<Bn * 8 * 8, 256, 0, stream>>>(
      Pm, HbT, out, Sv, Ln, Ln, Ln, DHn,
      (long)Tn * Ln, (long)DHn * Ln, (long)Tn * DHn, Tn, 1.f, 8);
}

// Round 5
// 421.044 us; speedup vs baseline: 1.0340x; 1.0340x over previous
//
#include <hip/hip_runtime.h>
#include <hip/hip_bf16.h>
#include <stdint.h>

// Problem dims
#define Bn  8
#define Ln  4096
#define DHn 1024
#define Tn  1024
#define DGn 768
#define Pn  256

typedef float  f32x4  __attribute__((ext_vector_type(4)));
typedef __bf16 bf16x8 __attribute__((ext_vector_type(8)));
typedef unsigned short u16x8 __attribute__((ext_vector_type(8)));

__device__ __forceinline__ void gload16(const void* g, void* l) {
  __builtin_amdgcn_global_load_lds(
      (const __attribute__((address_space(1))) void*)g,
      (__attribute__((address_space(3))) void*)l, 16, 0, 0);
}

__device__ __forceinline__ unsigned short f2bf(float x) {
  union { float f; uint32_t u; } v; v.f = x;
  uint32_t u = v.u;
  return (unsigned short)((u + 0x7FFFu + ((u >> 16) & 1u)) >> 16);
}

__device__ __forceinline__ float bf2f(unsigned short b) {
  union { uint32_t u; float f; } v; v.u = ((uint32_t)b) << 16;
  return v.f;
}

// ---------------- fused fp32 -> bf16 convert for G, Wq, Wk (one launch) ----------------
__global__ void cvt3_kernel(const float4* __restrict__ a, ushort4* __restrict__ ao, int na4,
                            const float4* __restrict__ b, ushort4* __restrict__ bo, int nb4,
                            const float4* __restrict__ c, ushort4* __restrict__ co, int nc4) {
  int i = blockIdx.x * 256 + threadIdx.x;
  const float4* s; ushort4* d; int j;
  if (i < na4)                  { s = a; d = ao; j = i; }
  else if (i < na4 + nb4)       { s = b; d = bo; j = i - na4; }
  else if (i < na4 + nb4 + nc4) { s = c; d = co; j = i - na4 - nb4; }
  else return;
  float4 v = s[j];
  ushort4 o;
  o.x = f2bf(v.x); o.y = f2bf(v.y); o.z = f2bf(v.z); o.w = f2bf(v.w);
  d[j] = o;
}

// ------- H [B,L,DH] fp32 -> Hb [B,L,DH] bf16 AND HT [B,DH,L] bf16, one read -------
// R7: widened to 32B reads / 16B stores per lane (was 16B/8B) — halves the
// transaction count on 256MB of traffic. Odd LDS stride (65) spreads the
// transpose-write banks (~2-way worst case, free per m136).
__global__ void prep_H(const float* __restrict__ Hg,
                       unsigned short* __restrict__ Hb,
                       unsigned short* __restrict__ HT) {
  __shared__ unsigned short tile[64 * 65];
  const int b  = blockIdx.z;
  const int l0 = blockIdx.x * 64;
  const int d0 = blockIdx.y * 64;
  const float4* src = (const float4*)(Hg + (size_t)b * Ln * DHn);
  unsigned short* dstH = Hb + (size_t)b * Ln * DHn;
  for (int e = threadIdx.x; e < 512; e += 256) {
    int l  = e >> 3;          // 64 rows
    int d8 = e & 7;           // 8 x 8-wide d chunks
    size_t base = (size_t)(l0 + l) * DHn + d0 + d8 * 8;
    float4 v0 = src[base / 4], v1 = src[base / 4 + 1];
    u16x8 o;
    o[0] = f2bf(v0.x); o[1] = f2bf(v0.y); o[2] = f2bf(v0.z); o[3] = f2bf(v0.w);
    o[4] = f2bf(v1.x); o[5] = f2bf(v1.y); o[6] = f2bf(v1.z); o[7] = f2bf(v1.w);
    *(u16x8*)(dstH + base) = o;   // straight bf16 copy, 16B store
    int d = d8 * 8;
#pragma unroll
    for (int j = 0; j < 8; ++j) tile[(d + j) * 65 + l] = o[j];
  }
  __syncthreads();
  unsigned short* dstT = HT + (size_t)b * DHn * Ln;
  for (int e = threadIdx.x; e < 512; e += 256) {
    int d  = e >> 3;          // 64 d-rows
    int l8 = (e & 7) * 8;     // 8 x 8-wide l chunks
    u16x8 o;
#pragma unroll
    for (int j = 0; j < 8; ++j) o[j] = tile[d * 65 + l8 + j];
    *(u16x8*)(dstT + (size_t)(d0 + d) * Ln + l0 + l8) = o;  // 16B store
  }
}

// ---------- bt-GEMM: C[m,n] = sum_k A[m,k]*B[n,k], 128 x (NT*32) tile, BK k-step ----------
// Flat grid, batch-on-XCD swizzle: b = x&7, then n-tile innermost (consecutive
// blocks on one XCD share the A-tile -> L2-resident re-reads).
// 2-barrier single-buffer structure. R6/R8 post-mortems: explicit dbuf (R6,
// 93->167us) and 128x128 tile at 2 blk/CU (R8, 93->105us) BOTH regress Z —
// latency hiding comes from >=4 blocks/CU of inter-block TLP, which requires
// the 128x64 tile's grid (1024 blocks). Tile-vs-residency trade-off is now
// measured on both sides: NT2@4/CU=739TF > NT4@2/CU=654TF.
// Bank-conflict-free staging swizzles (R3 verified conflicts 8.4M -> 0):
//   BK=32: row stride 64B; lane stages kgroup (lane&3)^((lane>>3)&3);
//          fragment slot = quad^((lrow>>1)&3).
//   BK=64: row stride 128B (banks wrap per row); lane stages kgroup
//          (lane&7)^((lane>>3)&7); fragment slot = (h*4+quad)^(lrow&7).
// R9: EPI0/1 epilogues bounce the C-tile through (reused) LDS and flush with
// 16B/lane ushort8 stores in 128-256B contiguous segments — the direct
// fragment stores were single-u16/lane at 32B segment granularity (4x L2
// request amplification on QK's 64MB P write).
// EPI 0: C bf16 = acc
// EPI 1: C bf16 = exp(acc*scale), row-sums atomically added into S
// EPI 2: C fp32 = acc / (S[row] + 1e-8)
template <int EPI, int NT, int BK>
__global__ __launch_bounds__(256) void gemm_bt(
    const unsigned short* __restrict__ A, const unsigned short* __restrict__ B,
    void* __restrict__ Cout, float* __restrict__ S,
    int kLen, int lda, int ldb, int ldc,
    long sA, long sB, long sC, int sS, float scale, int nTiles) {
  constexpr int Nn  = NT * 32;             // block n-extent
  constexpr int RPC = 1024 / (BK * 2);     // rows per 1KB staging chunk
  constexpr int APW = (128 * BK * 2 / 1024) / 4;  // A chunks per wave
  constexpr int BPW = (Nn  * BK * 2 / 1024) / 4;  // B chunks per wave
  constexpr int STGU = 128 * BK + Nn * BK;        // staging u16s
  constexpr int EPBU = (EPI <= 1) ? 128 * Nn : 0; // epilogue C-tile u16s
  constexpr int SMEMU = STGU > EPBU ? STGU : EPBU;
  __shared__ unsigned short smem[SMEMU];
  unsigned short* As = smem;
  unsigned short* Bs = smem + 128 * BK;
  int x = blockIdx.x;
  const int b = x & (Bn - 1);
  int r = x >> 3;
  const int ni = r % nTiles;
  const int mi = r / nTiles;
  const unsigned short* Ab = A + (long)b * sA;
  const unsigned short* Bb = B + (long)b * sB;
  const int m0 = mi * 128;
  const int n0 = ni * Nn;
  const int tid  = threadIdx.x;
  const int lane = tid & 63;
  const int wave = tid >> 6;
  const int wm = (wave >> 1) << 6;        // wave m-offset (2 waves over 128 rows)
  const int wn = (wave & 1) * (NT * 16);  // wave n-offset (2 waves over Nn cols)
  const int lrow = lane & 15;
  const int quad = lane >> 4;
  // staging: row within chunk + swizzled k-offset (see header comment)
  const int srow  = (BK == 32) ? (lane >> 2) : (lane >> 3);
  const int skcol = (BK == 32)
      ? (((lane & 3) ^ ((lane >> 3) & 3)) << 3)
      : (((lane & 7) ^ ((lane >> 3) & 7)) << 3);

  f32x4 acc[4][NT];
#pragma unroll
  for (int mt = 0; mt < 4; ++mt)
#pragma unroll
    for (int nt = 0; nt < NT; ++nt) acc[mt][nt] = f32x4{0.f, 0.f, 0.f, 0.f};

  for (int k0 = 0; k0 < kLen; k0 += BK) {
    __syncthreads();
#pragma unroll
    for (int j = 0; j < APW; ++j) {
      int c = wave * APW + j;
      gload16(Ab + (size_t)(m0 + c * RPC + srow) * lda + (k0 + skcol), &As[c * 512]);
    }
#pragma unroll
    for (int j = 0; j < BPW; ++j) {
      int c = wave * BPW + j;
      gload16(Bb + (size_t)(n0 + c * RPC + srow) * ldb + (k0 + skcol), &Bs[c * 512]);
    }
    __syncthreads();
#pragma unroll
    for (int h = 0; h < BK / 32; ++h) {
      const int fsl = (BK == 32)
          ? ((quad ^ ((lrow >> 1) & 3)) << 3)
          : ((((h << 2) + quad) ^ (lrow & 7)) << 3);
      bf16x8 af[4], bfr[NT];
#pragma unroll
      for (int mt = 0; mt < 4; ++mt)
        af[mt] = *(const bf16x8*)&As[(wm + mt * 16 + lrow) * BK + fsl];
#pragma unroll
      for (int nt = 0; nt < NT; ++nt)
        bfr[nt] = *(const bf16x8*)&Bs[(wn + nt * 16 + lrow) * BK + fsl];
#pragma unroll
      for (int mt = 0; mt < 4; ++mt)
#pragma unroll
        for (int nt = 0; nt < NT; ++nt)
          acc[mt][nt] = __builtin_amdgcn_mfma_f32_16x16x32_bf16(
              af[mt], bfr[nt], acc[mt][nt], 0, 0, 0);
    }
  }

  // C/D layout (verified m89/m91): col = lane&15, row = quad*4 + reg
  if (EPI == 0) {
    unsigned short* C = (unsigned short*)Cout + (long)b * sC;
    __syncthreads();  // staging dead -> reuse smem as C-tile [128][Nn]
#pragma unroll
    for (int mt = 0; mt < 4; ++mt)
#pragma unroll
      for (int r2 = 0; r2 < 4; ++r2) {
        int lr = wm + mt * 16 + quad * 4 + r2;
#pragma unroll
        for (int nt = 0; nt < NT; ++nt)
          smem[lr * Nn + wn + nt * 16 + lrow] = f2bf(acc[mt][nt][r2]);
      }
    __syncthreads();
    constexpr int UPR = Nn / 8;  // ushort8 units per row
    for (int u = tid; u < 128 * UPR; u += 256) {
      int rr = u / UPR, c8 = (u % UPR) * 8;
      *(u16x8*)(C + (size_t)(m0 + rr) * ldc + n0 + c8) =
          *(const u16x8*)&smem[rr * Nn + c8];
    }
  } else if (EPI == 1) {
    unsigned short* C = (unsigned short*)Cout + (long)b * sC;
    float* Sb = S + (long)b * sS;
    __syncthreads();  // staging dead -> reuse smem as C-tile [128][Nn]
#pragma unroll
    for (int mt = 0; mt < 4; ++mt)
#pragma unroll
      for (int r2 = 0; r2 < 4; ++r2) {
        int lr = wm + mt * 16 + quad * 4 + r2;
        float psum = 0.f;
#pragma unroll
        for (int nt = 0; nt < NT; ++nt) {
          float e = __expf(acc[mt][nt][r2] * scale);
          unsigned short bv = f2bf(e);
          smem[lr * Nn + wn + nt * 16 + lrow] = bv;
          psum += bf2f(bv);  // sum the value we actually stored
        }
        psum += __shfl_xor(psum, 1);
        psum += __shfl_xor(psum, 2);
        psum += __shfl_xor(psum, 4);
        psum += __shfl_xor(psum, 8);
        if (lrow == 0) atomicAdd(&Sb[m0 + lr], psum);
      }
    __syncthreads();
    constexpr int UPR = Nn / 8;
    for (int u = tid; u < 128 * UPR; u += 256) {
      int rr = u / UPR, c8 = (u % UPR) * 8;
      *(u16x8*)(C + (size_t)(m0 + rr) * ldc + n0 + c8) =
          *(const u16x8*)&smem[rr * Nn + c8];
    }
  } else {
    float* C = (float*)Cout + (long)b * sC;
    const float* Sb = S + (long)b * sS;
#pragma unroll
    for (int mt = 0; mt < 4; ++mt)
#pragma unroll
      for (int r2 = 0; r2 < 4; ++r2) {
        int row = m0 + wm + mt * 16 + quad * 4 + r2;
        float inv = 1.f / (Sb[row] + 1e-8f);
        float* Cr = C + (size_t)row * ldc + n0 + wn + lrow;
#pragma unroll
        for (int nt = 0; nt < NT; ++nt) Cr[nt * 16] = acc[mt][nt][r2] * inv;
      }
  }
}

extern "C" void kernel_launch(void* const* d_in, const int* in_sizes, int n_in,
                              void* d_out, int out_size, void* d_ws, size_t ws_size,
                              hipStream_t stream) {
  const float* H  = (const float*)d_in[0];
  const float* G  = (const float*)d_in[1];
  const float* Wq = (const float*)d_in[2];
  const float* Wk = (const float*)d_in[3];
  float* out = (float*)d_out;

  char* ws = (char*)d_ws;
  size_t off = 0;
  auto alloc = [&](size_t bytes) {
    void* p = ws + off;
    off = (off + bytes + 255) & ~(size_t)255;
    return p;
  };
  unsigned short* Hb  = (unsigned short*)alloc((size_t)Bn * Ln * DHn * 2); // 64MB
  unsigned short* HbT = (unsigned short*)alloc((size_t)Bn * DHn * Ln * 2); // 64MB
  unsigned short* Gb  = (unsigned short*)alloc((size_t)Bn * Tn * DGn * 2); // 12MB
  unsigned short* Wqb = (unsigned short*)alloc((size_t)Pn * DGn * 2);
  unsigned short* Wkb = (unsigned short*)alloc((size_t)Pn * DHn * 2);
  unsigned short* Kb  = (unsigned short*)alloc((size_t)Bn * Ln * Pn * 2);  // 16MB
  unsigned short* Qb  = (unsigned short*)alloc((size_t)Bn * Tn * Pn * 2);  // 4MB
  float* Sv           = (float*)alloc((size_t)Bn * Tn * 4);                // 32KB
  // P [B,T,L] bf16 (64MB) aliases Hb: Hb is dead after K-proj, and same-stream
  // kernels serialize, so QK's writes can't race K-proj's reads.
  unsigned short* Pm = Hb;

  // 1) fused small converts (G, Wq, Wk) in one launch
  {
    int na4 = Bn * Tn * DGn / 4;   // 1572864
    int nb4 = Pn * DGn / 4;        // 49152
    int nc4 = Pn * DHn / 4;        // 65536
    int tot = na4 + nb4 + nc4;     // 1687552 = 6592 * 256
    cvt3_kernel<<<(tot + 255) / 256, 256, 0, stream>>>(
        (const float4*)G, (ushort4*)Gb, na4,
        (const float4*)Wq, (ushort4*)Wqb, nb4,
        (const float4*)Wk, (ushort4*)Wkb, nc4);
  }
  // 2) fused H convert + transpose (reads H fp32 exactly once)
  prep_H<<<dim3(Ln / 64, DHn / 64, Bn), 256, 0, stream>>>(H, Hb, HbT);
  // 3) zero softmax sums
  hipMemsetAsync(Sv, 0, (size_t)Bn * Tn * 4, stream);

  // 4) K = H Wk^T : [L,P] per batch, 128x64 tiles, BK=64 (32 x 4 x 8 = 1024 blocks)
  gemm_bt<0, 2, 64><<<Bn * 32 * 4, 256, 0, stream>>>(
      Hb, Wkb, Kb, nullptr, DHn, DHn, DHn, Pn,
      (long)Ln * DHn, 0L, (long)Ln * Pn, 0, 1.f, 4);
  // 5) Q = G Wq^T : [T,P] per batch, 128x32 tiles, BK=64 (8 x 8 x 8 = 512 blocks)
  gemm_bt<0, 1, 64><<<Bn * 8 * 8, 256, 0, stream>>>(
      Gb, Wqb, Qb, nullptr, DGn, DGn, DGn, Pn,
      (long)Tn * DGn, 0L, (long)Tn * Pn, 0, 1.f, 8);
  // 6) P = exp(scale * Q K^T) : [T,L], 128x128 tiles, BK=32 (8 x 32 x 8 = 2048
  //    blocks) — round-2 anchor config; LDS 32KB (epi bounce) keeps 5 blk/CU
  gemm_bt<1, 4, 32><<<Bn * 8 * 32, 256, 0, stream>>>(
      Qb, Kb, Pm, Sv, Pn, Pn, Pn, Ln,
      (long)Tn * Pn, (long)Ln * Pn, (long)Tn * Ln, Tn, 0.0625f, 32);
  // 7) Z = (P H) / (s + eps) : [T,DH], 128x64 tiles, BK=64 (8 x 16 x 8 = 1024
  //    blocks, 4/CU — measured optimum, see template header)
  gemm_bt<2, 2, 64><<<Bn * 8 * 16, 256, 0, stream>>>(
      Pm, HbT, out, Sv, Ln, Ln, Ln, DHn,
      (long)Tn * Ln, (long)DHn * Ln, (long)Tn * DHn, Tn, 1.f, 16);
}